// Round 1
// baseline (370.608 us; speedup 1.0000x reference)
//
#include <hip/hip_runtime.h>

#define NN 50000
#define NE 500000
#define NT 11
#define D  128
#define OD 64
#define NG 512
#define SCAN_B 512

// ---------- degree / normalization ----------
__global__ void k_deg(const int* __restrict__ dst, int* __restrict__ deg) {
  int e = blockIdx.x * 256 + threadIdx.x;
  if (e < NE) atomicAdd(&deg[dst[e]], 1);
}

__global__ void k_dinv(const int* __restrict__ deg, float* __restrict__ dinv) {
  int i = blockIdx.x * 256 + threadIdx.x;
  if (i < NN) dinv[i] = rsqrtf((float)deg[i] + 1.0f);
}

// ---------- exclusive prefix scan over deg -> CSR offsets ----------
__global__ void k_scan1(const int* __restrict__ x, int* __restrict__ incl,
                        int* __restrict__ bsum, int n) {
  __shared__ int s[SCAN_B];
  int t = threadIdx.x;
  int gid = blockIdx.x * SCAN_B + t;
  int v = (gid < n) ? x[gid] : 0;
  s[t] = v;
  __syncthreads();
  for (int off = 1; off < SCAN_B; off <<= 1) {
    int u = (t >= off) ? s[t - off] : 0;
    __syncthreads();
    s[t] += u;
    __syncthreads();
  }
  if (gid < n) incl[gid] = s[t];
  if (t == SCAN_B - 1) bsum[blockIdx.x] = s[t];
}

__global__ void k_scan2(int* __restrict__ bsum, int nb) {
  __shared__ int s[128];
  int t = threadIdx.x;
  int v = (t < nb) ? bsum[t] : 0;
  s[t] = v;
  __syncthreads();
  for (int off = 1; off < 128; off <<= 1) {
    int u = (t >= off) ? s[t - off] : 0;
    __syncthreads();
    s[t] += u;
    __syncthreads();
  }
  if (t < nb) bsum[t] = s[t] - v;  // exclusive
}

__global__ void k_scan3(const int* __restrict__ x, const int* __restrict__ incl,
                        const int* __restrict__ boff, int* __restrict__ offs, int n) {
  int gid = blockIdx.x * 256 + threadIdx.x;
  if (gid < n) {
    int inc = incl[gid] + boff[gid / SCAN_B];
    offs[gid] = inc - x[gid];
    if (gid == n - 1) offs[n] = inc;
  }
}

// ---------- counting-sort edges into CSR (by dst) ----------
__global__ void k_csr(const int* __restrict__ src, const int* __restrict__ dst,
                      const float* __restrict__ dinv, const int* __restrict__ offs,
                      int* __restrict__ cur, int* __restrict__ csr_s,
                      float* __restrict__ csr_w) {
  int e = blockIdx.x * 256 + threadIdx.x;
  if (e < NE) {
    int s = src[e], d = dst[e];
    int pos = offs[d] + atomicAdd(&cur[d], 1);
    csr_s[pos] = s;
    csr_w[pos] = dinv[s] * dinv[d];
  }
}

// ---------- layer 0: EW = embed @ W0 (11x128), then gather by atom type ----------
__global__ void k_ew0(const float* __restrict__ embed, const float* __restrict__ W0,
                      float* __restrict__ EW) {
  int r = blockIdx.x, c = threadIdx.x;
  float acc = 0.f;
  for (int k = 0; k < D; ++k) acc += embed[r * D + k] * W0[k * D + c];
  EW[r * D + c] = acc;
}

__global__ void k_gather(const int* __restrict__ x, const float4* __restrict__ EW,
                         float4* __restrict__ t) {
  int idx = blockIdx.x * 256 + threadIdx.x;
  if (idx < NN * 32) {
    int n = idx >> 5;
    t[idx] = EW[(x[n] << 5) + (idx & 31)];
  }
}

// ---------- fp32 GEMM: C[M,128] = A[M,128] @ W[128,128] ----------
__launch_bounds__(256)
__global__ void k_gemm(const float* __restrict__ A, const float* __restrict__ W,
                       float* __restrict__ C) {
  __shared__ float As[64][36];    // +4 pad keeps 16B alignment, spreads banks
  __shared__ float Bs[32][128];
  int tid = threadIdx.x;
  int bm = blockIdx.x * 64;
  int tx = tid & 15;   // 16 col-groups of 8
  int ty = tid >> 4;   // 16 row-groups of 4
  float acc[4][8];
#pragma unroll
  for (int i = 0; i < 4; ++i)
#pragma unroll
    for (int j = 0; j < 8; ++j) acc[i][j] = 0.f;

  for (int k0 = 0; k0 < D; k0 += 32) {
#pragma unroll
    for (int i = 0; i < 2; ++i) {          // A tile: 64x32 = 512 float4
      int f = tid + i * 256;
      int r = f >> 3, c4 = (f & 7) << 2;
      int row = bm + r;
      float4 v = make_float4(0.f, 0.f, 0.f, 0.f);
      if (row < NN) v = *(const float4*)(A + row * D + k0 + c4);
      *(float4*)(&As[r][c4]) = v;
    }
#pragma unroll
    for (int i = 0; i < 4; ++i) {          // W tile: 32x128 = 1024 float4
      int f = tid + i * 256;
      int r = f >> 5, c4 = (f & 31) << 2;
      *(float4*)(&Bs[r][c4]) = *(const float4*)(W + (k0 + r) * D + c4);
    }
    __syncthreads();
#pragma unroll
    for (int kk = 0; kk < 32; ++kk) {
      float a[4], bb[8];
#pragma unroll
      for (int i = 0; i < 4; ++i) a[i] = As[ty * 4 + i][kk];
      float4 q0 = *(float4*)&Bs[kk][tx * 8];
      float4 q1 = *(float4*)&Bs[kk][tx * 8 + 4];
      bb[0] = q0.x; bb[1] = q0.y; bb[2] = q0.z; bb[3] = q0.w;
      bb[4] = q1.x; bb[5] = q1.y; bb[6] = q1.z; bb[7] = q1.w;
#pragma unroll
      for (int i = 0; i < 4; ++i)
#pragma unroll
        for (int j = 0; j < 8; ++j) acc[i][j] += a[i] * bb[j];
    }
    __syncthreads();
  }
#pragma unroll
  for (int i = 0; i < 4; ++i) {
    int row = bm + ty * 4 + i;
    if (row < NN) {
      float4 o0 = make_float4(acc[i][0], acc[i][1], acc[i][2], acc[i][3]);
      float4 o1 = make_float4(acc[i][4], acc[i][5], acc[i][6], acc[i][7]);
      *(float4*)(C + row * D + tx * 8) = o0;
      *(float4*)(C + row * D + tx * 8 + 4) = o1;
    }
  }
}

// ---------- aggregation: h[n] = relu(sum_e t[src]*w + t[n]*dinv[n]^2 + b) ----------
__global__ void k_agg(const float* __restrict__ t, float* __restrict__ h,
                      const int* __restrict__ offs, const int* __restrict__ csr_s,
                      const float* __restrict__ csr_w, const float* __restrict__ dinv,
                      const float* __restrict__ b) {
  int n = blockIdx.x, c = threadIdx.x;
  float dn = dinv[n];
  float acc = t[n * D + c] * dn * dn;
  int e0 = offs[n], e1 = offs[n + 1];
  for (int e = e0; e < e1; ++e) {
    acc += t[csr_s[e] * D + c] * csr_w[e];
  }
  h[n * D + c] = fmaxf(acc + b[c], 0.f);
}

// ---------- graph start offsets from sorted batch ----------
__global__ void k_gs(const int* __restrict__ batch, int* __restrict__ gs) {
  int i = blockIdx.x * 256 + threadIdx.x;
  if (i >= NN) return;
  int b = batch[i];
  if (i == 0) {
    for (int g = 0; g <= b; ++g) gs[g] = 0;
  } else {
    int bp = batch[i - 1];
    for (int g = bp + 1; g <= b; ++g) gs[g] = i;
  }
  if (i == NN - 1) {
    for (int g = b + 1; g <= NG; ++g) gs[g] = NN;
  }
}

// ---------- fused mean-pool + fc ----------
__global__ void k_pool(const float* __restrict__ h, const int* __restrict__ gs,
                       const float* __restrict__ fw, const float* __restrict__ fb,
                       float* __restrict__ out) {
  __shared__ float p[D];
  int g = blockIdx.x, t = threadIdx.x;
  int s = gs[g], e = gs[g + 1];
  float acc = 0.f;
  for (int n = s; n < e; ++n) acc += h[n * D + t];
  int cnt = e - s;
  acc /= (float)(cnt > 0 ? cnt : 1);
  p[t] = acc;
  __syncthreads();
  if (t < OD) {
    float o = fb[t];
    for (int k = 0; k < D; ++k) o += p[k] * fw[k * OD + t];
    out[g * OD + t] = o;
  }
}

extern "C" void kernel_launch(void* const* d_in, const int* in_sizes, int n_in,
                              void* d_out, int out_size, void* d_ws, size_t ws_size,
                              hipStream_t stream) {
  const int* x     = (const int*)d_in[0];
  const int* ei    = (const int*)d_in[1];
  const int* batch = (const int*)d_in[2];
  const float* embed = (const float*)d_in[3];
  const float* W0  = (const float*)d_in[4];
  const float* b0  = (const float*)d_in[5];
  const float* W1  = (const float*)d_in[6];
  const float* b1  = (const float*)d_in[7];
  const float* W2  = (const float*)d_in[8];
  const float* b2  = (const float*)d_in[9];
  const float* fw  = (const float*)d_in[10];
  const float* fb  = (const float*)d_in[11];
  float* out = (float*)d_out;
  const int* src = ei;
  const int* dst = ei + NE;

  char* p = (char*)d_ws;
  auto alloc = [&](size_t bytes) {
    char* r = p;
    p += (bytes + 255) & ~(size_t)255;
    return r;
  };
  float* h     = (float*)alloc((size_t)NN * D * 4);
  float* tbuf  = (float*)alloc((size_t)NN * D * 4);
  int*   deg   = (int*)alloc((size_t)NN * 4);
  float* dinv  = (float*)alloc((size_t)NN * 4);
  int*   offs  = (int*)alloc((size_t)(NN + 1) * 4);
  int*   cur   = (int*)alloc((size_t)NN * 4);
  int*   csr_s = (int*)alloc((size_t)NE * 4);
  float* csr_w = (float*)alloc((size_t)NE * 4);
  float* EW    = (float*)alloc((size_t)NT * D * 4);
  int*   incl  = (int*)alloc((size_t)NN * 4);
  int*   bsum  = (int*)alloc(128 * 4);
  int*   gs    = (int*)alloc((size_t)(NG + 1) * 4);

  hipMemsetAsync(deg, 0, (size_t)NN * 4, stream);
  hipMemsetAsync(cur, 0, (size_t)NN * 4, stream);

  int eb = (NE + 255) / 256;
  int nb = (NN + 255) / 256;
  int sb = (NN + SCAN_B - 1) / SCAN_B;  // 98 blocks

  k_deg<<<eb, 256, 0, stream>>>(dst, deg);
  k_dinv<<<nb, 256, 0, stream>>>(deg, dinv);
  k_scan1<<<sb, SCAN_B, 0, stream>>>(deg, incl, bsum, NN);
  k_scan2<<<1, 128, 0, stream>>>(bsum, sb);
  k_scan3<<<nb, 256, 0, stream>>>(deg, incl, bsum, offs, NN);
  k_csr<<<eb, 256, 0, stream>>>(src, dst, dinv, offs, cur, csr_s, csr_w);

  // layer 0: h0@W0 == (embed@W0)[x]
  k_ew0<<<NT, D, 0, stream>>>(embed, W0, EW);
  k_gather<<<(NN * 32 + 255) / 256, 256, 0, stream>>>(x, (const float4*)EW, (float4*)tbuf);
  k_agg<<<NN, D, 0, stream>>>(tbuf, h, offs, csr_s, csr_w, dinv, b0);

  // layer 1
  k_gemm<<<(NN + 63) / 64, 256, 0, stream>>>(h, W1, tbuf);
  k_agg<<<NN, D, 0, stream>>>(tbuf, h, offs, csr_s, csr_w, dinv, b1);

  // layer 2
  k_gemm<<<(NN + 63) / 64, 256, 0, stream>>>(h, W2, tbuf);
  k_agg<<<NN, D, 0, stream>>>(tbuf, h, offs, csr_s, csr_w, dinv, b2);

  // pooling + fc
  k_gs<<<nb, 256, 0, stream>>>(batch, gs);
  k_pool<<<NG, D, 0, stream>>>(h, gs, fw, fb, out);
}

// Round 2
// 287.683 us; speedup vs baseline: 1.2883x; 1.2883x over previous
//
#include <hip/hip_runtime.h>

#define NN 50000
#define NE 500000
#define NT 11
#define D  128
#define OD 64
#define NG 512
#define SCAN_B 512

// ---------- degree / normalization ----------
__global__ void k_deg(const int* __restrict__ dst, int* __restrict__ deg) {
  int e = blockIdx.x * 256 + threadIdx.x;
  if (e < NE) atomicAdd(&deg[dst[e]], 1);
}

__global__ void k_dinv(const int* __restrict__ deg, float* __restrict__ dinv) {
  int i = blockIdx.x * 256 + threadIdx.x;
  if (i < NN) dinv[i] = rsqrtf((float)deg[i] + 1.0f);
}

// ---------- exclusive prefix scan over deg -> CSR offsets ----------
__global__ void k_scan1(const int* __restrict__ x, int* __restrict__ incl,
                        int* __restrict__ bsum, int n) {
  __shared__ int s[SCAN_B];
  int t = threadIdx.x;
  int gid = blockIdx.x * SCAN_B + t;
  int v = (gid < n) ? x[gid] : 0;
  s[t] = v;
  __syncthreads();
  for (int off = 1; off < SCAN_B; off <<= 1) {
    int u = (t >= off) ? s[t - off] : 0;
    __syncthreads();
    s[t] += u;
    __syncthreads();
  }
  if (gid < n) incl[gid] = s[t];
  if (t == SCAN_B - 1) bsum[blockIdx.x] = s[t];
}

__global__ void k_scan2(int* __restrict__ bsum, int nb) {
  __shared__ int s[128];
  int t = threadIdx.x;
  int v = (t < nb) ? bsum[t] : 0;
  s[t] = v;
  __syncthreads();
  for (int off = 1; off < 128; off <<= 1) {
    int u = (t >= off) ? s[t - off] : 0;
    __syncthreads();
    s[t] += u;
    __syncthreads();
  }
  if (t < nb) bsum[t] = s[t] - v;  // exclusive
}

__global__ void k_scan3(const int* __restrict__ x, const int* __restrict__ incl,
                        const int* __restrict__ boff, int* __restrict__ offs, int n) {
  int gid = blockIdx.x * 256 + threadIdx.x;
  if (gid < n) {
    int inc = incl[gid] + boff[gid / SCAN_B];
    offs[gid] = inc - x[gid];
    if (gid == n - 1) offs[n] = inc;
  }
}

// ---------- counting-sort edges into CSR (by dst) ----------
__global__ void k_csr(const int* __restrict__ src, const int* __restrict__ dst,
                      const int* __restrict__ offs, int* __restrict__ cur,
                      int* __restrict__ csr_s) {
  int e = blockIdx.x * 256 + threadIdx.x;
  if (e < NE) {
    int s = src[e], d = dst[e];
    int pos = offs[d] + atomicAdd(&cur[d], 1);
    csr_s[pos] = s;
  }
}

// ---------- EW = embed @ W0 (11x128) ----------
__global__ void k_ew0(const float* __restrict__ embed, const float* __restrict__ W0,
                      float* __restrict__ EW) {
  int r = blockIdx.x, c = threadIdx.x;
  float acc = 0.f;
  for (int k = 0; k < D; ++k) acc += embed[r * D + k] * W0[k * D + c];
  EW[r * D + c] = acc;
}

// ---------- layer-0 aggregation straight from the 11-row EW table ----------
// h[n] = relu(dinv[n] * (sum_e EW[x[s]]*dinv[s] + EW[x[n]]*dinv[n]) + b)
__launch_bounds__(256)
__global__ void k_agg0(const float* __restrict__ EW, const int* __restrict__ x,
                       const float* __restrict__ dinv, float* __restrict__ h,
                       const int* __restrict__ offs, const int* __restrict__ csr_s,
                       const float* __restrict__ b) {
  __shared__ float sEW[NT * D];
  int tid = threadIdx.x;
  for (int i = tid; i < NT * D; i += 256) sEW[i] = EW[i];
  __syncthreads();
  int n = blockIdx.x * 4 + (tid >> 6);
  int lane = tid & 63;
  if (n >= NN) return;
  float dn = dinv[n];
  const float2* selfr = (const float2*)(sEW + x[n] * D);
  float2 sv = selfr[lane];
  float ax = sv.x * dn, ay = sv.y * dn;
  float a0x = 0.f, a0y = 0.f, a1x = 0.f, a1y = 0.f;
  float a2x = 0.f, a2y = 0.f, a3x = 0.f, a3y = 0.f;
  int e0 = offs[n], e1 = offs[n + 1];
  int e = e0;
  for (; e + 3 < e1; e += 4) {
    int s0 = csr_s[e], s1 = csr_s[e + 1], s2 = csr_s[e + 2], s3 = csr_s[e + 3];
    float w0 = dinv[s0], w1 = dinv[s1], w2 = dinv[s2], w3 = dinv[s3];
    int x0 = x[s0], x1 = x[s1], x2 = x[s2], x3 = x[s3];
    float2 v0 = ((const float2*)(sEW + x0 * D))[lane];
    float2 v1 = ((const float2*)(sEW + x1 * D))[lane];
    float2 v2 = ((const float2*)(sEW + x2 * D))[lane];
    float2 v3 = ((const float2*)(sEW + x3 * D))[lane];
    a0x += v0.x * w0; a0y += v0.y * w0;
    a1x += v1.x * w1; a1y += v1.y * w1;
    a2x += v2.x * w2; a2y += v2.y * w2;
    a3x += v3.x * w3; a3y += v3.y * w3;
  }
  for (; e < e1; ++e) {
    int s = csr_s[e];
    float w = dinv[s];
    float2 v = ((const float2*)(sEW + x[s] * D))[lane];
    ax += v.x * w; ay += v.y * w;
  }
  ax += (a0x + a1x) + (a2x + a3x);
  ay += (a0y + a1y) + (a2y + a3y);
  float2 bb = ((const float2*)b)[lane];
  float2 o;
  o.x = fmaxf(ax * dn + bb.x, 0.f);
  o.y = fmaxf(ay * dn + bb.y, 0.f);
  ((float2*)(h + n * D))[lane] = o;
}

// ---------- fp32 GEMM + dinv pre-scale: ts[M,128] = (A[M,128] @ W) * dinv[row] ----------
__launch_bounds__(256)
__global__ void k_gemm(const float* __restrict__ A, const float* __restrict__ W,
                       const float* __restrict__ dinv, float* __restrict__ C) {
  __shared__ float As[64][36];
  __shared__ float Bs[32][128];
  int tid = threadIdx.x;
  int bm = blockIdx.x * 64;
  int tx = tid & 15;
  int ty = tid >> 4;
  float acc[4][8];
#pragma unroll
  for (int i = 0; i < 4; ++i)
#pragma unroll
    for (int j = 0; j < 8; ++j) acc[i][j] = 0.f;

  for (int k0 = 0; k0 < D; k0 += 32) {
#pragma unroll
    for (int i = 0; i < 2; ++i) {
      int f = tid + i * 256;
      int r = f >> 3, c4 = (f & 7) << 2;
      int row = bm + r;
      float4 v = make_float4(0.f, 0.f, 0.f, 0.f);
      if (row < NN) v = *(const float4*)(A + row * D + k0 + c4);
      *(float4*)(&As[r][c4]) = v;
    }
#pragma unroll
    for (int i = 0; i < 4; ++i) {
      int f = tid + i * 256;
      int r = f >> 5, c4 = (f & 31) << 2;
      *(float4*)(&Bs[r][c4]) = *(const float4*)(W + (k0 + r) * D + c4);
    }
    __syncthreads();
#pragma unroll
    for (int kk = 0; kk < 32; ++kk) {
      float a[4], bb[8];
#pragma unroll
      for (int i = 0; i < 4; ++i) a[i] = As[ty * 4 + i][kk];
      float4 q0 = *(float4*)&Bs[kk][tx * 8];
      float4 q1 = *(float4*)&Bs[kk][tx * 8 + 4];
      bb[0] = q0.x; bb[1] = q0.y; bb[2] = q0.z; bb[3] = q0.w;
      bb[4] = q1.x; bb[5] = q1.y; bb[6] = q1.z; bb[7] = q1.w;
#pragma unroll
      for (int i = 0; i < 4; ++i)
#pragma unroll
        for (int j = 0; j < 8; ++j) acc[i][j] += a[i] * bb[j];
    }
    __syncthreads();
  }
#pragma unroll
  for (int i = 0; i < 4; ++i) {
    int row = bm + ty * 4 + i;
    if (row < NN) {
      float dv = dinv[row];
      float4 o0 = make_float4(acc[i][0] * dv, acc[i][1] * dv, acc[i][2] * dv, acc[i][3] * dv);
      float4 o1 = make_float4(acc[i][4] * dv, acc[i][5] * dv, acc[i][6] * dv, acc[i][7] * dv);
      *(float4*)(C + row * D + tx * 8) = o0;
      *(float4*)(C + row * D + tx * 8 + 4) = o1;
    }
  }
}

// ---------- aggregation over pre-scaled ts: h[n]=relu(dinv[n]*(Σ ts[s] + ts[n]) + b) ----------
// one wave per node; float2/lane = one 512B row per load; unroll 4 for MLP
__launch_bounds__(256)
__global__ void k_agg2(const float* __restrict__ ts, float* __restrict__ h,
                       const int* __restrict__ offs, const int* __restrict__ csr_s,
                       const float* __restrict__ dinv, const float* __restrict__ b) {
  int tid = threadIdx.x;
  int n = blockIdx.x * 4 + (tid >> 6);
  int lane = tid & 63;
  float2 sv = ((const float2*)(ts + (size_t)n * D))[lane];
  float ax = sv.x, ay = sv.y;
  float a0x = 0.f, a0y = 0.f, a1x = 0.f, a1y = 0.f;
  float a2x = 0.f, a2y = 0.f, a3x = 0.f, a3y = 0.f;
  int e0 = offs[n], e1 = offs[n + 1];
  int e = e0;
  for (; e + 3 < e1; e += 4) {
    int s0 = csr_s[e], s1 = csr_s[e + 1], s2 = csr_s[e + 2], s3 = csr_s[e + 3];
    float2 v0 = ((const float2*)(ts + (size_t)s0 * D))[lane];
    float2 v1 = ((const float2*)(ts + (size_t)s1 * D))[lane];
    float2 v2 = ((const float2*)(ts + (size_t)s2 * D))[lane];
    float2 v3 = ((const float2*)(ts + (size_t)s3 * D))[lane];
    a0x += v0.x; a0y += v0.y;
    a1x += v1.x; a1y += v1.y;
    a2x += v2.x; a2y += v2.y;
    a3x += v3.x; a3y += v3.y;
  }
  for (; e < e1; ++e) {
    int s = csr_s[e];
    float2 v = ((const float2*)(ts + (size_t)s * D))[lane];
    ax += v.x; ay += v.y;
  }
  ax += (a0x + a1x) + (a2x + a3x);
  ay += (a0y + a1y) + (a2y + a3y);
  float dn = dinv[n];
  float2 bb = ((const float2*)b)[lane];
  float2 o;
  o.x = fmaxf(ax * dn + bb.x, 0.f);
  o.y = fmaxf(ay * dn + bb.y, 0.f);
  ((float2*)(h + (size_t)n * D))[lane] = o;
}

// ---------- graph start offsets from sorted batch ----------
__global__ void k_gs(const int* __restrict__ batch, int* __restrict__ gs) {
  int i = blockIdx.x * 256 + threadIdx.x;
  if (i >= NN) return;
  int b = batch[i];
  if (i == 0) {
    for (int g = 0; g <= b; ++g) gs[g] = 0;
  } else {
    int bp = batch[i - 1];
    for (int g = bp + 1; g <= b; ++g) gs[g] = i;
  }
  if (i == NN - 1) {
    for (int g = b + 1; g <= NG; ++g) gs[g] = NN;
  }
}

// ---------- fused mean-pool + fc ----------
__global__ void k_pool(const float* __restrict__ h, const int* __restrict__ gs,
                       const float* __restrict__ fw, const float* __restrict__ fb,
                       float* __restrict__ out) {
  __shared__ float p[D];
  int g = blockIdx.x, t = threadIdx.x;
  int s = gs[g], e = gs[g + 1];
  float acc = 0.f;
  for (int n = s; n < e; ++n) acc += h[n * D + t];
  int cnt = e - s;
  acc /= (float)(cnt > 0 ? cnt : 1);
  p[t] = acc;
  __syncthreads();
  if (t < OD) {
    float o = fb[t];
    for (int k = 0; k < D; ++k) o += p[k] * fw[k * OD + t];
    out[g * OD + t] = o;
  }
}

extern "C" void kernel_launch(void* const* d_in, const int* in_sizes, int n_in,
                              void* d_out, int out_size, void* d_ws, size_t ws_size,
                              hipStream_t stream) {
  const int* x     = (const int*)d_in[0];
  const int* ei    = (const int*)d_in[1];
  const int* batch = (const int*)d_in[2];
  const float* embed = (const float*)d_in[3];
  const float* W0  = (const float*)d_in[4];
  const float* b0  = (const float*)d_in[5];
  const float* W1  = (const float*)d_in[6];
  const float* b1  = (const float*)d_in[7];
  const float* W2  = (const float*)d_in[8];
  const float* b2  = (const float*)d_in[9];
  const float* fw  = (const float*)d_in[10];
  const float* fb  = (const float*)d_in[11];
  float* out = (float*)d_out;
  const int* src = ei;
  const int* dst = ei + NE;

  char* p = (char*)d_ws;
  auto alloc = [&](size_t bytes) {
    char* r = p;
    p += (bytes + 255) & ~(size_t)255;
    return r;
  };
  float* h     = (float*)alloc((size_t)NN * D * 4);
  float* tbuf  = (float*)alloc((size_t)NN * D * 4);
  int*   deg   = (int*)alloc((size_t)NN * 4);
  float* dinv  = (float*)alloc((size_t)NN * 4);
  int*   offs  = (int*)alloc((size_t)(NN + 1) * 4);
  int*   cur   = (int*)alloc((size_t)NN * 4);
  int*   csr_s = (int*)alloc((size_t)NE * 4);
  float* EW    = (float*)alloc((size_t)NT * D * 4);
  int*   incl  = (int*)alloc((size_t)NN * 4);
  int*   bsum  = (int*)alloc(128 * 4);
  int*   gs    = (int*)alloc((size_t)(NG + 1) * 4);

  hipMemsetAsync(deg, 0, (size_t)NN * 4, stream);
  hipMemsetAsync(cur, 0, (size_t)NN * 4, stream);

  int eb = (NE + 255) / 256;
  int nb = (NN + 255) / 256;
  int sb = (NN + SCAN_B - 1) / SCAN_B;  // 98 blocks

  k_deg<<<eb, 256, 0, stream>>>(dst, deg);
  k_dinv<<<nb, 256, 0, stream>>>(deg, dinv);
  k_scan1<<<sb, SCAN_B, 0, stream>>>(deg, incl, bsum, NN);
  k_scan2<<<1, 128, 0, stream>>>(bsum, sb);
  k_scan3<<<nb, 256, 0, stream>>>(deg, incl, bsum, offs, NN);
  k_csr<<<eb, 256, 0, stream>>>(src, dst, offs, cur, csr_s);

  // layer 0: h0@W0 == (embed@W0)[x]; aggregate straight from the 11-row table
  k_ew0<<<NT, D, 0, stream>>>(embed, W0, EW);
  k_agg0<<<NN / 4, 256, 0, stream>>>(EW, x, dinv, h, offs, csr_s, b0);

  // layer 1: ts = (h@W1)*dinv, then h = relu(dinv*(Σ ts[s] + ts[n]) + b1)
  k_gemm<<<(NN + 63) / 64, 256, 0, stream>>>(h, W1, dinv, tbuf);
  k_agg2<<<NN / 4, 256, 0, stream>>>(tbuf, h, offs, csr_s, dinv, b1);

  // layer 2
  k_gemm<<<(NN + 63) / 64, 256, 0, stream>>>(h, W2, dinv, tbuf);
  k_agg2<<<NN / 4, 256, 0, stream>>>(tbuf, h, offs, csr_s, dinv, b2);

  // pooling + fc
  k_gs<<<nb, 256, 0, stream>>>(batch, gs);
  k_pool<<<NG, D, 0, stream>>>(h, gs, fw, fb, out);
}

// Round 3
// 259.742 us; speedup vs baseline: 1.4268x; 1.1076x over previous
//
#include <hip/hip_runtime.h>

#define NN 50000
#define NE 500000
#define NT 11
#define D  128
#define OD 64
#define NG 512
#define SCAN_B 512

typedef __attribute__((ext_vector_type(8))) short short8;
typedef __attribute__((ext_vector_type(4))) float f32x4;

static __device__ __forceinline__ unsigned short f2b(float f) {
  unsigned u = __float_as_uint(f);
  return (unsigned short)((u + 0x7fffu + ((u >> 16) & 1u)) >> 16);
}
static __device__ __forceinline__ float b2f_lo(unsigned u) {
  return __uint_as_float(u << 16);
}
static __device__ __forceinline__ float b2f_hi(unsigned u) {
  return __uint_as_float(u & 0xffff0000u);
}

// ---------- degree ----------
__global__ void k_deg(const int* __restrict__ dst, int* __restrict__ deg) {
  int e = blockIdx.x * 256 + threadIdx.x;
  if (e < NE) atomicAdd(&deg[dst[e]], 1);
}

// ---------- exclusive prefix scan over deg -> CSR offsets ----------
__global__ void k_scan1(const int* __restrict__ x, int* __restrict__ incl,
                        int* __restrict__ bsum, int n) {
  __shared__ int s[SCAN_B];
  int t = threadIdx.x;
  int gid = blockIdx.x * SCAN_B + t;
  int v = (gid < n) ? x[gid] : 0;
  s[t] = v;
  __syncthreads();
  for (int off = 1; off < SCAN_B; off <<= 1) {
    int u = (t >= off) ? s[t - off] : 0;
    __syncthreads();
    s[t] += u;
    __syncthreads();
  }
  if (gid < n) incl[gid] = s[t];
  if (t == SCAN_B - 1) bsum[blockIdx.x] = s[t];
}

__global__ void k_scan2(int* __restrict__ bsum, int nb) {
  __shared__ int s[128];
  int t = threadIdx.x;
  int v = (t < nb) ? bsum[t] : 0;
  s[t] = v;
  __syncthreads();
  for (int off = 1; off < 128; off <<= 1) {
    int u = (t >= off) ? s[t - off] : 0;
    __syncthreads();
    s[t] += u;
    __syncthreads();
  }
  if (t < nb) bsum[t] = s[t] - v;  // exclusive
}

// scan3 + fused dinv
__global__ void k_scan3(const int* __restrict__ x, const int* __restrict__ incl,
                        const int* __restrict__ boff, int* __restrict__ offs,
                        float* __restrict__ dinv, int n) {
  int gid = blockIdx.x * 256 + threadIdx.x;
  if (gid < n) {
    int inc = incl[gid] + boff[gid / SCAN_B];
    offs[gid] = inc - x[gid];
    dinv[gid] = rsqrtf((float)x[gid] + 1.0f);
    if (gid == n - 1) offs[n] = inc;
  }
}

// ---------- counting-sort edges into CSR (by dst) ----------
__global__ void k_csr(const int* __restrict__ src, const int* __restrict__ dst,
                      const int* __restrict__ offs, int* __restrict__ cur,
                      int* __restrict__ csr_s) {
  int e = blockIdx.x * 256 + threadIdx.x;
  if (e < NE) {
    int s = src[e], d = dst[e];
    int pos = offs[d] + atomicAdd(&cur[d], 1);
    csr_s[pos] = s;
  }
}

// ---------- EW = embed @ W0 (11x128) ----------
__global__ void k_ew0(const float* __restrict__ embed, const float* __restrict__ W0,
                      float* __restrict__ EW) {
  int r = blockIdx.x, c = threadIdx.x;
  float acc = 0.f;
  for (int k = 0; k < D; ++k) acc += embed[r * D + k] * W0[k * D + c];
  EW[r * D + c] = acc;
}

// ---------- W^T bf16 prep: WT[c][k] = bf16(W[k][c]) for W1 and W2 ----------
__global__ void k_wprep(const float* __restrict__ W1, const float* __restrict__ W2,
                        unsigned short* __restrict__ WT1, unsigned short* __restrict__ WT2) {
  int idx = blockIdx.x * 256 + threadIdx.x;  // 0..32767
  const float* W = (idx < D * D) ? W1 : W2;
  unsigned short* WT = (idx < D * D) ? WT1 : WT2;
  int i = idx & (D * D - 1);
  int k = i >> 7, c = i & 127;
  WT[c * D + k] = f2b(W[k * D + c]);
}

// ---------- layer-0 aggregation straight from the 11-row EW table ----------
__launch_bounds__(256)
__global__ void k_agg0(const float* __restrict__ EW, const int* __restrict__ x,
                       const float* __restrict__ dinv, float* __restrict__ h,
                       const int* __restrict__ offs, const int* __restrict__ csr_s,
                       const float* __restrict__ b) {
  __shared__ float sEW[NT * D];
  int tid = threadIdx.x;
  for (int i = tid; i < NT * D; i += 256) sEW[i] = EW[i];
  __syncthreads();
  int n = blockIdx.x * 4 + (tid >> 6);
  int lane = tid & 63;
  float dn = dinv[n];
  float2 sv = ((const float2*)(sEW + x[n] * D))[lane];
  float ax = sv.x * dn, ay = sv.y * dn;
  float a0x = 0.f, a0y = 0.f, a1x = 0.f, a1y = 0.f;
  float a2x = 0.f, a2y = 0.f, a3x = 0.f, a3y = 0.f;
  int e0 = offs[n], e1 = offs[n + 1];
  int e = e0;
  for (; e + 3 < e1; e += 4) {
    int s0 = csr_s[e], s1 = csr_s[e + 1], s2 = csr_s[e + 2], s3 = csr_s[e + 3];
    float w0 = dinv[s0], w1 = dinv[s1], w2 = dinv[s2], w3 = dinv[s3];
    int x0 = x[s0], x1 = x[s1], x2 = x[s2], x3 = x[s3];
    float2 v0 = ((const float2*)(sEW + x0 * D))[lane];
    float2 v1 = ((const float2*)(sEW + x1 * D))[lane];
    float2 v2 = ((const float2*)(sEW + x2 * D))[lane];
    float2 v3 = ((const float2*)(sEW + x3 * D))[lane];
    a0x += v0.x * w0; a0y += v0.y * w0;
    a1x += v1.x * w1; a1y += v1.y * w1;
    a2x += v2.x * w2; a2y += v2.y * w2;
    a3x += v3.x * w3; a3y += v3.y * w3;
  }
  for (; e < e1; ++e) {
    int s = csr_s[e];
    float w = dinv[s];
    float2 v = ((const float2*)(sEW + x[s] * D))[lane];
    ax += v.x * w; ay += v.y * w;
  }
  ax += (a0x + a1x) + (a2x + a3x);
  ay += (a0y + a1y) + (a2y + a3y);
  float2 bb = ((const float2*)b)[lane];
  float2 o;
  o.x = fmaxf(ax * dn + bb.x, 0.f);
  o.y = fmaxf(ay * dn + bb.y, 0.f);
  ((float2*)(h + n * D))[lane] = o;
}

// ---------- MFMA GEMM: ts[M][128] = bf16( (A[M][128] @ W) * dinv[row] ) ----------
// A f32 row-major; WT = W^T bf16 (L2-resident, no LDS).
// frag maps (verified m89/m92 convention):
//   a: A[l&15][8*(l>>4)+i]   b: B[8*(l>>4)+i][l&15] = WT[l&15][8*(l>>4)+i]
//   d: row=4*(l>>4)+r, col=l&15
__launch_bounds__(256)
__global__ void k_gemm(const float* __restrict__ A, const unsigned short* __restrict__ WT,
                       const float* __restrict__ dinv, unsigned short* __restrict__ ts) {
  int tid = threadIdx.x;
  int w = tid >> 6, lane = tid & 63;
  int l15 = lane & 15, l4 = lane >> 4;
  int bm = blockIdx.x * 64;
  int arow = bm + (w << 4) + l15;
  const float* ap = A + (size_t)arow * D + (l4 << 3);

  f32x4 acc[8];
#pragma unroll
  for (int ct = 0; ct < 8; ++ct) acc[ct] = (f32x4){0.f, 0.f, 0.f, 0.f};

#pragma unroll
  for (int ks = 0; ks < 4; ++ks) {
    float4 f0 = make_float4(0.f, 0.f, 0.f, 0.f);
    float4 f1 = f0;
    if (arow < NN) {
      f0 = *(const float4*)(ap + ks * 32);
      f1 = *(const float4*)(ap + ks * 32 + 4);
    }
    short8 a;
    a[0] = (short)f2b(f0.x); a[1] = (short)f2b(f0.y);
    a[2] = (short)f2b(f0.z); a[3] = (short)f2b(f0.w);
    a[4] = (short)f2b(f1.x); a[5] = (short)f2b(f1.y);
    a[6] = (short)f2b(f1.z); a[7] = (short)f2b(f1.w);
#pragma unroll
    for (int ct = 0; ct < 8; ++ct) {
      short8 bfr = *(const short8*)(WT + ((ct << 4) + l15) * D + ks * 32 + (l4 << 3));
      acc[ct] = __builtin_amdgcn_mfma_f32_16x16x32_bf16(a, bfr, acc[ct], 0, 0, 0);
    }
  }

#pragma unroll
  for (int r = 0; r < 4; ++r) {
    int orow = bm + (w << 4) + (l4 << 2) + r;
    if (orow < NN) {
      float dv = dinv[orow];
      unsigned short* op = ts + (size_t)orow * D + l15;
#pragma unroll
      for (int ct = 0; ct < 8; ++ct) op[ct << 4] = f2b(acc[ct][r] * dv);
    }
  }
}

// ---------- aggregation over pre-scaled bf16 ts ----------
// h[n] = relu(dinv[n]*(sum_e ts[s] + ts[n]) + b), one wave/node, 1 dword/lane/row
__launch_bounds__(256)
__global__ void k_agg2(const unsigned short* __restrict__ ts, float* __restrict__ h,
                       const int* __restrict__ offs, const int* __restrict__ csr_s,
                       const float* __restrict__ dinv, const float* __restrict__ b) {
  int tid = threadIdx.x;
  int n = blockIdx.x * 4 + (tid >> 6);
  int lane = tid & 63;
  unsigned su = ((const unsigned*)(ts + (size_t)n * D))[lane];
  float ax = b2f_lo(su), ay = b2f_hi(su);
  float a0x = 0.f, a0y = 0.f, a1x = 0.f, a1y = 0.f;
  float a2x = 0.f, a2y = 0.f, a3x = 0.f, a3y = 0.f;
  int e0 = offs[n], e1 = offs[n + 1];
  int e = e0;
  for (; e + 3 < e1; e += 4) {
    int s0 = csr_s[e], s1 = csr_s[e + 1], s2 = csr_s[e + 2], s3 = csr_s[e + 3];
    unsigned u0 = ((const unsigned*)(ts + (size_t)s0 * D))[lane];
    unsigned u1 = ((const unsigned*)(ts + (size_t)s1 * D))[lane];
    unsigned u2 = ((const unsigned*)(ts + (size_t)s2 * D))[lane];
    unsigned u3 = ((const unsigned*)(ts + (size_t)s3 * D))[lane];
    a0x += b2f_lo(u0); a0y += b2f_hi(u0);
    a1x += b2f_lo(u1); a1y += b2f_hi(u1);
    a2x += b2f_lo(u2); a2y += b2f_hi(u2);
    a3x += b2f_lo(u3); a3y += b2f_hi(u3);
  }
  for (; e < e1; ++e) {
    int s = csr_s[e];
    unsigned u = ((const unsigned*)(ts + (size_t)s * D))[lane];
    ax += b2f_lo(u); ay += b2f_hi(u);
  }
  ax += (a0x + a1x) + (a2x + a3x);
  ay += (a0y + a1y) + (a2y + a3y);
  float dn = dinv[n];
  float2 bb = ((const float2*)b)[lane];
  float2 o;
  o.x = fmaxf(ax * dn + bb.x, 0.f);
  o.y = fmaxf(ay * dn + bb.y, 0.f);
  ((float2*)(h + (size_t)n * D))[lane] = o;
}

// ---------- graph start offsets from sorted batch ----------
__global__ void k_gs(const int* __restrict__ batch, int* __restrict__ gs) {
  int i = blockIdx.x * 256 + threadIdx.x;
  if (i >= NN) return;
  int b = batch[i];
  if (i == 0) {
    for (int g = 0; g <= b; ++g) gs[g] = 0;
  } else {
    int bp = batch[i - 1];
    for (int g = bp + 1; g <= b; ++g) gs[g] = i;
  }
  if (i == NN - 1) {
    for (int g = b + 1; g <= NG; ++g) gs[g] = NN;
  }
}

// ---------- fused mean-pool + fc ----------
__global__ void k_pool(const float* __restrict__ h, const int* __restrict__ gs,
                       const float* __restrict__ fw, const float* __restrict__ fb,
                       float* __restrict__ out) {
  __shared__ float p[D];
  int g = blockIdx.x, t = threadIdx.x;
  int s = gs[g], e = gs[g + 1];
  float acc = 0.f;
  for (int n = s; n < e; ++n) acc += h[n * D + t];
  int cnt = e - s;
  acc /= (float)(cnt > 0 ? cnt : 1);
  p[t] = acc;
  __syncthreads();
  if (t < OD) {
    float o = fb[t];
    for (int k = 0; k < D; ++k) o += p[k] * fw[k * OD + t];
    out[g * OD + t] = o;
  }
}

extern "C" void kernel_launch(void* const* d_in, const int* in_sizes, int n_in,
                              void* d_out, int out_size, void* d_ws, size_t ws_size,
                              hipStream_t stream) {
  const int* x     = (const int*)d_in[0];
  const int* ei    = (const int*)d_in[1];
  const int* batch = (const int*)d_in[2];
  const float* embed = (const float*)d_in[3];
  const float* W0  = (const float*)d_in[4];
  const float* b0  = (const float*)d_in[5];
  const float* W1  = (const float*)d_in[6];
  const float* b1  = (const float*)d_in[7];
  const float* W2  = (const float*)d_in[8];
  const float* b2  = (const float*)d_in[9];
  const float* fw  = (const float*)d_in[10];
  const float* fb  = (const float*)d_in[11];
  float* out = (float*)d_out;
  const int* src = ei;
  const int* dst = ei + NE;

  char* p = (char*)d_ws;
  auto alloc = [&](size_t bytes) {
    char* r = p;
    p += (bytes + 255) & ~(size_t)255;
    return r;
  };
  float* h     = (float*)alloc((size_t)NN * D * 4);
  unsigned short* ts = (unsigned short*)alloc((size_t)NN * D * 2);
  int*   deg   = (int*)alloc((size_t)NN * 4);
  float* dinv  = (float*)alloc((size_t)NN * 4);
  int*   offs  = (int*)alloc((size_t)(NN + 1) * 4);
  int*   cur   = (int*)alloc((size_t)NN * 4);
  int*   csr_s = (int*)alloc((size_t)NE * 4);
  float* EW    = (float*)alloc((size_t)NT * D * 4);
  unsigned short* WT1 = (unsigned short*)alloc((size_t)D * D * 2);
  unsigned short* WT2 = (unsigned short*)alloc((size_t)D * D * 2);
  int*   incl  = (int*)alloc((size_t)NN * 4);
  int*   bsum  = (int*)alloc(128 * 4);
  int*   gs    = (int*)alloc((size_t)(NG + 1) * 4);

  hipMemsetAsync(deg, 0, (size_t)NN * 4, stream);
  hipMemsetAsync(cur, 0, (size_t)NN * 4, stream);

  int eb = (NE + 255) / 256;
  int nb = (NN + 255) / 256;
  int sb = (NN + SCAN_B - 1) / SCAN_B;  // 98 blocks

  k_deg<<<eb, 256, 0, stream>>>(dst, deg);
  k_scan1<<<sb, SCAN_B, 0, stream>>>(deg, incl, bsum, NN);
  k_scan2<<<1, 128, 0, stream>>>(bsum, sb);
  k_scan3<<<nb, 256, 0, stream>>>(deg, incl, bsum, offs, dinv, NN);
  k_csr<<<eb, 256, 0, stream>>>(src, dst, offs, cur, csr_s);

  k_ew0<<<NT, D, 0, stream>>>(embed, W0, EW);
  k_wprep<<<(2 * D * D) / 256, 256, 0, stream>>>(W1, W2, WT1, WT2);

  // layer 0
  k_agg0<<<NN / 4, 256, 0, stream>>>(EW, x, dinv, h, offs, csr_s, b0);
  // layer 1
  k_gemm<<<(NN + 63) / 64, 256, 0, stream>>>(h, WT1, dinv, ts);
  k_agg2<<<NN / 4, 256, 0, stream>>>(ts, h, offs, csr_s, dinv, b1);
  // layer 2
  k_gemm<<<(NN + 63) / 64, 256, 0, stream>>>(h, WT2, dinv, ts);
  k_agg2<<<NN / 4, 256, 0, stream>>>(ts, h, offs, csr_s, dinv, b2);

  // pooling + fc
  k_gs<<<nb, 256, 0, stream>>>(batch, gs);
  k_pool<<<NG, D, 0, stream>>>(h, gs, fw, fb, out);
}

// Round 4
// 230.677 us; speedup vs baseline: 1.6066x; 1.1260x over previous
//
#include <hip/hip_runtime.h>

#define NN 50000
#define NE 500000
#define NT 11
#define D  128
#define OD 64
#define NG 512
#define SCAN_B 512

typedef __attribute__((ext_vector_type(8))) short short8;
typedef __attribute__((ext_vector_type(4))) float f32x4;

static __device__ __forceinline__ unsigned short f2b(float f) {
  unsigned u = __float_as_uint(f);
  return (unsigned short)((u + 0x7fffu + ((u >> 16) & 1u)) >> 16);
}
static __device__ __forceinline__ float b2f_lo(unsigned u) {
  return __uint_as_float(u << 16);
}
static __device__ __forceinline__ float b2f_hi(unsigned u) {
  return __uint_as_float(u & 0xffff0000u);
}
static __device__ __forceinline__ unsigned pack2(float lo, float hi) {
  return (unsigned)f2b(lo) | ((unsigned)f2b(hi) << 16);
}

// ---------- degree ----------
__global__ void k_deg(const int* __restrict__ dst, int* __restrict__ deg) {
  int e = blockIdx.x * 256 + threadIdx.x;
  if (e < NE) atomicAdd(&deg[dst[e]], 1);
}

// ---------- exclusive prefix scan over deg -> CSR offsets ----------
__global__ void k_scan1(const int* __restrict__ x, int* __restrict__ incl,
                        int* __restrict__ bsum, int n) {
  __shared__ int s[SCAN_B];
  int t = threadIdx.x;
  int gid = blockIdx.x * SCAN_B + t;
  int v = (gid < n) ? x[gid] : 0;
  s[t] = v;
  __syncthreads();
  for (int off = 1; off < SCAN_B; off <<= 1) {
    int u = (t >= off) ? s[t - off] : 0;
    __syncthreads();
    s[t] += u;
    __syncthreads();
  }
  if (gid < n) incl[gid] = s[t];
  if (t == SCAN_B - 1) bsum[blockIdx.x] = s[t];
}

__global__ void k_scan2(int* __restrict__ bsum, int nb) {
  __shared__ int s[128];
  int t = threadIdx.x;
  int v = (t < nb) ? bsum[t] : 0;
  s[t] = v;
  __syncthreads();
  for (int off = 1; off < 128; off <<= 1) {
    int u = (t >= off) ? s[t - off] : 0;
    __syncthreads();
    s[t] += u;
    __syncthreads();
  }
  if (t < nb) bsum[t] = s[t] - v;  // exclusive
}

// scan3 + fused dinv
__global__ void k_scan3(const int* __restrict__ x, const int* __restrict__ incl,
                        const int* __restrict__ boff, int* __restrict__ offs,
                        float* __restrict__ dinv, int n) {
  int gid = blockIdx.x * 256 + threadIdx.x;
  if (gid < n) {
    int inc = incl[gid] + boff[gid / SCAN_B];
    offs[gid] = inc - x[gid];
    dinv[gid] = rsqrtf((float)x[gid] + 1.0f);
    if (gid == n - 1) offs[n] = inc;
  }
}

// ---------- counting-sort edges into CSR (by dst) + per-edge payload ----------
__global__ void k_csr(const int* __restrict__ src, const int* __restrict__ dst,
                      const int* __restrict__ x, const float* __restrict__ dinv,
                      const int* __restrict__ offs, int* __restrict__ cur,
                      int* __restrict__ csr_s, int2* __restrict__ csr_xd) {
  int e = blockIdx.x * 256 + threadIdx.x;
  if (e < NE) {
    int s = src[e], d = dst[e];
    int pos = offs[d] + atomicAdd(&cur[d], 1);
    csr_s[pos] = s;
    csr_xd[pos] = make_int2(x[s], __float_as_int(dinv[s]));
  }
}

// ---------- fused prep: WT1/WT2 = W^T bf16; EW = embed @ W0 ----------
__global__ void k_prep(const float* __restrict__ embed, const float* __restrict__ W0,
                       const float* __restrict__ W1, const float* __restrict__ W2,
                       float* __restrict__ EW, unsigned short* __restrict__ WT1,
                       unsigned short* __restrict__ WT2) {
  int idx = blockIdx.x * 256 + threadIdx.x;
  if (idx < 2 * D * D) {
    const float* W = (idx < D * D) ? W1 : W2;
    unsigned short* WT = (idx < D * D) ? WT1 : WT2;
    int i = idx & (D * D - 1);
    int k = i >> 7, c = i & 127;
    WT[c * D + k] = f2b(W[k * D + c]);
  } else if (idx < 2 * D * D + NT * D) {
    int i = idx - 2 * D * D;
    int r = i >> 7, c = i & 127;
    float acc = 0.f;
    for (int k = 0; k < D; ++k) acc += embed[r * D + k] * W0[k * D + c];
    EW[r * D + c] = acc;
  }
}

// ---------- layer-0 aggregation from 11-row EW table; all-scalar edge loop ----------
__launch_bounds__(256)
__global__ void k_agg0(const float* __restrict__ EW, const int* __restrict__ x,
                       const float* __restrict__ dinv, unsigned* __restrict__ h,
                       const int* __restrict__ offs, const int2* __restrict__ csr_xd,
                       const float* __restrict__ b) {
  __shared__ float sEW[NT * D];
  int tid = threadIdx.x;
  for (int i = tid; i < NT * D; i += 256) sEW[i] = EW[i];
  __syncthreads();
  int n = __builtin_amdgcn_readfirstlane(blockIdx.x * 4 + (tid >> 6));
  int lane = tid & 63;
  float dn = dinv[n];
  float2 sv = ((const float2*)(sEW + x[n] * D))[lane];
  float ax = sv.x * dn, ay = sv.y * dn;
  float a0x = 0.f, a0y = 0.f, a1x = 0.f, a1y = 0.f;
  float a2x = 0.f, a2y = 0.f, a3x = 0.f, a3y = 0.f;
  int e0 = offs[n], e1 = offs[n + 1];
  int e = e0;
  for (; e + 3 < e1; e += 4) {
    int2 p0 = csr_xd[e], p1 = csr_xd[e + 1], p2 = csr_xd[e + 2], p3 = csr_xd[e + 3];
    float w0 = __int_as_float(p0.y), w1 = __int_as_float(p1.y);
    float w2 = __int_as_float(p2.y), w3 = __int_as_float(p3.y);
    float2 v0 = ((const float2*)(sEW + p0.x * D))[lane];
    float2 v1 = ((const float2*)(sEW + p1.x * D))[lane];
    float2 v2 = ((const float2*)(sEW + p2.x * D))[lane];
    float2 v3 = ((const float2*)(sEW + p3.x * D))[lane];
    a0x += v0.x * w0; a0y += v0.y * w0;
    a1x += v1.x * w1; a1y += v1.y * w1;
    a2x += v2.x * w2; a2y += v2.y * w2;
    a3x += v3.x * w3; a3y += v3.y * w3;
  }
  for (; e < e1; ++e) {
    int2 pp = csr_xd[e];
    float w = __int_as_float(pp.y);
    float2 v = ((const float2*)(sEW + pp.x * D))[lane];
    ax += v.x * w; ay += v.y * w;
  }
  ax += (a0x + a1x) + (a2x + a3x);
  ay += (a0y + a1y) + (a2y + a3y);
  float2 bb = ((const float2*)b)[lane];
  float ox = fmaxf(ax * dn + bb.x, 0.f);
  float oy = fmaxf(ay * dn + bb.y, 0.f);
  h[(size_t)n * (D / 2) + lane] = pack2(ox, oy);
}

// ---------- MFMA GEMM: ts[M][128] = bf16( (Abf16[M][128] @ W) * dinv[row] ) ----------
// A bf16 row-major (h); WT = W^T bf16, L2-resident, no LDS.
//   a: A[l&15][8*(l>>4)+i]   b: WT[l&15][8*(l>>4)+i]   d: row=4*(l>>4)+r, col=l&15
__launch_bounds__(256)
__global__ void k_gemm(const unsigned short* __restrict__ A,
                       const unsigned short* __restrict__ WT,
                       const float* __restrict__ dinv, unsigned short* __restrict__ ts) {
  int tid = threadIdx.x;
  int w = tid >> 6, lane = tid & 63;
  int l15 = lane & 15, l4 = lane >> 4;
  int bm = blockIdx.x * 64;
  int arow = bm + (w << 4) + l15;
  const unsigned short* ap = A + (size_t)arow * D + (l4 << 3);

  f32x4 acc[8];
#pragma unroll
  for (int ct = 0; ct < 8; ++ct) acc[ct] = (f32x4){0.f, 0.f, 0.f, 0.f};

#pragma unroll
  for (int ks = 0; ks < 4; ++ks) {
    short8 a = (short8)0;
    if (arow < NN) a = *(const short8*)(ap + ks * 32);
#pragma unroll
    for (int ct = 0; ct < 8; ++ct) {
      short8 bfr = *(const short8*)(WT + ((ct << 4) + l15) * D + ks * 32 + (l4 << 3));
      acc[ct] = __builtin_amdgcn_mfma_f32_16x16x32_bf16(a, bfr, acc[ct], 0, 0, 0);
    }
  }

#pragma unroll
  for (int r = 0; r < 4; ++r) {
    int orow = bm + (w << 4) + (l4 << 2) + r;
    if (orow < NN) {
      float dv = dinv[orow];
      unsigned short* op = ts + (size_t)orow * D + l15;
#pragma unroll
      for (int ct = 0; ct < 8; ++ct) op[ct << 4] = f2b(acc[ct][r] * dv);
    }
  }
}

// ---------- aggregation over pre-scaled bf16 ts -> bf16 h ----------
__launch_bounds__(256)
__global__ void k_agg2(const unsigned short* __restrict__ ts, unsigned* __restrict__ h,
                       const int* __restrict__ offs, const int* __restrict__ csr_s,
                       const float* __restrict__ dinv, const float* __restrict__ b) {
  int tid = threadIdx.x;
  int n = __builtin_amdgcn_readfirstlane(blockIdx.x * 4 + (tid >> 6));
  int lane = tid & 63;
  unsigned su = ((const unsigned*)(ts + (size_t)n * D))[lane];
  float ax = b2f_lo(su), ay = b2f_hi(su);
  float a0x = 0.f, a0y = 0.f, a1x = 0.f, a1y = 0.f;
  float a2x = 0.f, a2y = 0.f, a3x = 0.f, a3y = 0.f;
  int e0 = offs[n], e1 = offs[n + 1];
  int e = e0;
  for (; e + 3 < e1; e += 4) {
    int s0 = csr_s[e], s1 = csr_s[e + 1], s2 = csr_s[e + 2], s3 = csr_s[e + 3];
    unsigned u0 = ((const unsigned*)(ts + (size_t)s0 * D))[lane];
    unsigned u1 = ((const unsigned*)(ts + (size_t)s1 * D))[lane];
    unsigned u2 = ((const unsigned*)(ts + (size_t)s2 * D))[lane];
    unsigned u3 = ((const unsigned*)(ts + (size_t)s3 * D))[lane];
    a0x += b2f_lo(u0); a0y += b2f_hi(u0);
    a1x += b2f_lo(u1); a1y += b2f_hi(u1);
    a2x += b2f_lo(u2); a2y += b2f_hi(u2);
    a3x += b2f_lo(u3); a3y += b2f_hi(u3);
  }
  for (; e < e1; ++e) {
    int s = csr_s[e];
    unsigned u = ((const unsigned*)(ts + (size_t)s * D))[lane];
    ax += b2f_lo(u); ay += b2f_hi(u);
  }
  ax += (a0x + a1x) + (a2x + a3x);
  ay += (a0y + a1y) + (a2y + a3y);
  float dn = dinv[n];
  float2 bb = ((const float2*)b)[lane];
  float ox = fmaxf(ax * dn + bb.x, 0.f);
  float oy = fmaxf(ay * dn + bb.y, 0.f);
  h[(size_t)n * (D / 2) + lane] = pack2(ox, oy);
}

// ---------- graph start offsets from sorted batch ----------
__global__ void k_gs(const int* __restrict__ batch, int* __restrict__ gs) {
  int i = blockIdx.x * 256 + threadIdx.x;
  if (i >= NN) return;
  int b = batch[i];
  if (i == 0) {
    for (int g = 0; g <= b; ++g) gs[g] = 0;
  } else {
    int bp = batch[i - 1];
    for (int g = bp + 1; g <= b; ++g) gs[g] = i;
  }
  if (i == NN - 1) {
    for (int g = b + 1; g <= NG; ++g) gs[g] = NN;
  }
}

// ---------- fused mean-pool + fc: one wave per graph, bf16 h rows ----------
__launch_bounds__(64)
__global__ void k_pool(const unsigned* __restrict__ h, const int* __restrict__ gs,
                       const float* __restrict__ fw, const float* __restrict__ fb,
                       float* __restrict__ out) {
  __shared__ float p[D];
  int g = blockIdx.x, lane = threadIdx.x;
  int s = gs[g], e = gs[g + 1];
  float px = 0.f, py = 0.f;
  for (int n = s; n < e; ++n) {
    unsigned u = h[(size_t)n * (D / 2) + lane];
    px += b2f_lo(u); py += b2f_hi(u);
  }
  int cnt = e - s;
  float inv = 1.f / (float)(cnt > 0 ? cnt : 1);
  p[lane * 2] = px * inv;
  p[lane * 2 + 1] = py * inv;
  __syncthreads();
  float o = fb[lane];
  for (int k = 0; k < D; ++k) o += p[k] * fw[k * OD + lane];
  out[g * OD + lane] = o;
}

extern "C" void kernel_launch(void* const* d_in, const int* in_sizes, int n_in,
                              void* d_out, int out_size, void* d_ws, size_t ws_size,
                              hipStream_t stream) {
  const int* x     = (const int*)d_in[0];
  const int* ei    = (const int*)d_in[1];
  const int* batch = (const int*)d_in[2];
  const float* embed = (const float*)d_in[3];
  const float* W0  = (const float*)d_in[4];
  const float* b0  = (const float*)d_in[5];
  const float* W1  = (const float*)d_in[6];
  const float* b1  = (const float*)d_in[7];
  const float* W2  = (const float*)d_in[8];
  const float* b2  = (const float*)d_in[9];
  const float* fw  = (const float*)d_in[10];
  const float* fb  = (const float*)d_in[11];
  float* out = (float*)d_out;
  const int* src = ei;
  const int* dst = ei + NE;

  char* p = (char*)d_ws;
  auto alloc = [&](size_t bytes) {
    char* r = p;
    p += (bytes + 255) & ~(size_t)255;
    return r;
  };
  unsigned* h  = (unsigned*)alloc((size_t)NN * D * 2);        // bf16 h
  unsigned short* ts = (unsigned short*)alloc((size_t)NN * D * 2);
  int*   deg   = (int*)alloc((size_t)NN * 4);
  int*   cur   = (int*)alloc((size_t)NN * 4);                  // adjacent to deg for 1 memset
  float* dinv  = (float*)alloc((size_t)NN * 4);
  int*   offs  = (int*)alloc((size_t)(NN + 1) * 4);
  int*   csr_s = (int*)alloc((size_t)NE * 4);
  int2*  csr_xd= (int2*)alloc((size_t)NE * 8);
  float* EW    = (float*)alloc((size_t)NT * D * 4);
  unsigned short* WT1 = (unsigned short*)alloc((size_t)D * D * 2);
  unsigned short* WT2 = (unsigned short*)alloc((size_t)D * D * 2);
  int*   incl  = (int*)alloc((size_t)NN * 4);
  int*   bsum  = (int*)alloc(128 * 4);
  int*   gs    = (int*)alloc((size_t)(NG + 1) * 4);

  hipMemsetAsync(deg, 0, (size_t)((char*)cur - (char*)deg) + (size_t)NN * 4, stream);

  int eb = (NE + 255) / 256;
  int nb = (NN + 255) / 256;
  int sb = (NN + SCAN_B - 1) / SCAN_B;  // 98 blocks

  k_deg<<<eb, 256, 0, stream>>>(dst, deg);
  k_scan1<<<sb, SCAN_B, 0, stream>>>(deg, incl, bsum, NN);
  k_scan2<<<1, 128, 0, stream>>>(bsum, sb);
  k_scan3<<<nb, 256, 0, stream>>>(deg, incl, bsum, offs, dinv, NN);
  k_csr<<<eb, 256, 0, stream>>>(src, dst, x, dinv, offs, cur, csr_s, csr_xd);
  k_prep<<<(2 * D * D + NT * D + 255) / 256, 256, 0, stream>>>(embed, W0, W1, W2, EW, WT1, WT2);

  // layer 0
  k_agg0<<<NN / 4, 256, 0, stream>>>(EW, x, dinv, h, offs, csr_xd, b0);
  // layer 1
  k_gemm<<<(NN + 63) / 64, 256, 0, stream>>>((const unsigned short*)h, WT1, dinv, ts);
  k_agg2<<<NN / 4, 256, 0, stream>>>(ts, h, offs, csr_s, dinv, b1);
  // layer 2
  k_gemm<<<(NN + 63) / 64, 256, 0, stream>>>((const unsigned short*)h, WT2, dinv, ts);
  k_agg2<<<NN / 4, 256, 0, stream>>>(ts, h, offs, csr_s, dinv, b2);

  // pooling + fc
  k_gs<<<nb, 256, 0, stream>>>(batch, gs);
  k_pool<<<NG, 64, 0, stream>>>(h, gs, fw, fb, out);
}